// Round 1
// baseline (2378.761 us; speedup 1.0000x reference)
//
#include <hip/hip_runtime.h>

#define KB 16
#define TILE 64
#define PB 65536L   // floats per 256x256 matrix

// C[b] = alpha * op(A[b]) * B[b] + beta_diag * I
// TRANSA=true : A stored [K][256] row-major, op(A)=A^T (used for G = M^T M)
// TRANSA=false: A stored [256][K] row-major, op(A)=A
// B always [K][256] row-major. C is 256x256 row-major.
template <bool TRANSA>
__global__ __launch_bounds__(256) void gemm_k(
    const float* __restrict__ Abase, long strideA,
    const float* __restrict__ Bbase, long strideB,
    float* __restrict__ Cbase, long strideC,
    int K, float alpha, float beta_diag) {
  __shared__ float As[KB][TILE + 4];
  __shared__ float Bs[KB][TILE + 4];

  const int tid = threadIdx.x;
  const int tx = tid & 15;        // 0..15 -> 4 cols each
  const int ty = tid >> 4;        // 0..15 -> 4 rows each
  const int i0 = (blockIdx.x >> 2) * TILE;
  const int j0 = (blockIdx.x & 3) * TILE;

  const float* A = Abase + (long)blockIdx.y * strideA;
  const float* B = Bbase + (long)blockIdx.y * strideB;
  float* C = Cbase + (long)blockIdx.y * strideC;

  float acc[4][4] = {};

  for (int k0 = 0; k0 < K; k0 += KB) {
    if (TRANSA) {
      // As[kk][r] = A[(k0+kk)*256 + i0 + r] : rows contiguous, coalesced
      const int kk = tid >> 4;
      const int c4 = (tid & 15) * 4;
      const float4 av = *(const float4*)&A[(long)(k0 + kk) * 256 + i0 + c4];
      *(float4*)&As[kk][c4] = av;
    } else {
      // As[kk][r] = A[(i0+r)*256 + k0 + kk] : transpose during LDS store
      const int r = tid >> 2;
      const int c4 = (tid & 3) * 4;
      const float4 av = *(const float4*)&A[(long)(i0 + r) * 256 + k0 + c4];
      As[c4 + 0][r] = av.x;
      As[c4 + 1][r] = av.y;
      As[c4 + 2][r] = av.z;
      As[c4 + 3][r] = av.w;
    }
    {
      const int kk = tid >> 4;
      const int c4 = (tid & 15) * 4;
      const float4 bv = *(const float4*)&B[(long)(k0 + kk) * 256 + j0 + c4];
      *(float4*)&Bs[kk][c4] = bv;
    }
    __syncthreads();

#pragma unroll
    for (int kk = 0; kk < KB; ++kk) {
      const float4 av = *(const float4*)&As[kk][ty * 4];
      const float4 bv = *(const float4*)&Bs[kk][tx * 4];
      float a[4] = {av.x, av.y, av.z, av.w};
      float b[4] = {bv.x, bv.y, bv.z, bv.w};
#pragma unroll
      for (int e = 0; e < 4; ++e)
#pragma unroll
        for (int f = 0; f < 4; ++f) acc[e][f] += a[e] * b[f];
    }
    __syncthreads();
  }

#pragma unroll
  for (int e = 0; e < 4; ++e) {
    const int i = i0 + ty * 4 + e;
    const int jb = j0 + tx * 4;
    float4 out;
    out.x = alpha * acc[e][0] + ((i == jb + 0) ? beta_diag : 0.f);
    out.y = alpha * acc[e][1] + ((i == jb + 1) ? beta_diag : 0.f);
    out.z = alpha * acc[e][2] + ((i == jb + 2) ? beta_diag : 0.f);
    out.w = alpha * acc[e][3] + ((i == jb + 3) ? beta_diag : 0.f);
    *(float4*)&C[(long)i * 256 + jb] = out;
  }
}

__device__ __forceinline__ float block_reduce_sum(float val, float* red) {
  const int t = threadIdx.x;
  red[t] = val;
  __syncthreads();
  for (int s = 128; s > 0; s >>= 1) {
    if (t < s) red[t] += red[t + s];
    __syncthreads();
  }
  const float r = red[0];
  __syncthreads();
  return r;
}

// Power iteration (6 steps) -> Rayleigh quotient lambda_max estimate.
// s = 1.10 * lambda_R  (Rayleigh never exceeds lambda_max; NS converges for
// normalized eigenvalues in (0,3), so 1.10 headroom is far more than enough).
__global__ __launch_bounds__(256) void pow_iter_k(
    const float* __restrict__ Gbase, float* __restrict__ sinv,
    float* __restrict__ ssq) {
  const int b = blockIdx.x;
  const float* G = Gbase + (long)b * PB;
  __shared__ float v[256];
  __shared__ float red[256];
  const int i = threadIdx.x;
  v[i] = 1.0f;
  __syncthreads();
  float lam = 1.0f;
  for (int it = 0; it < 6; ++it) {
    float w = 0.f;
#pragma unroll 8
    for (int j = 0; j < 256; ++j) w += G[(long)j * 256 + i] * v[j];  // G sym
    const float vw = block_reduce_sum(v[i] * w, red);
    const float ww = block_reduce_sum(w * w, red);
    lam = vw;  // Rayleigh (v is unit from previous normalize; final iters matter)
    const float inv = rsqrtf(fmaxf(ww, 1e-30f));
    v[i] = w * inv;
    __syncthreads();
  }
  if (i == 0) {
    const float s = 1.10f * lam;
    sinv[b] = 1.0f / s;
    ssq[b] = sqrtf(s);
  }
}

// Y *= sinv[b] (in place, Y holds G), Z = I
__global__ __launch_bounds__(256) void init_yz_k(float* __restrict__ Y,
                                                 float* __restrict__ Z,
                                                 const float* __restrict__ sinv) {
  const long idx = (long)blockIdx.x * 256 + threadIdx.x;
  const int b = (int)(idx >> 16);
  const int w = (int)(idx & 65535);
  const int i = w >> 8, j = w & 255;
  Y[idx] *= sinv[b];
  Z[idx] = (i == j) ? 1.0f : 0.0f;
}

__global__ __launch_bounds__(256) void trace_k(const float* __restrict__ Y,
                                               const float* __restrict__ ssq,
                                               float* __restrict__ accum) {
  const int b = blockIdx.x;
  __shared__ float red[256];
  const int i = threadIdx.x;
  const float d = Y[(long)b * PB + (long)i * 257];
  const float tr = block_reduce_sum(d, red);
  if (i == 0) atomicAdd(accum, ssq[b] * tr);
}

__global__ void zero_k(float* a) {
  if (threadIdx.x == 0) a[0] = 0.f;
}

__global__ void fin_k(const float* __restrict__ accum, float* __restrict__ out) {
  if (threadIdx.x == 0) out[0] = accum[0] * (1e-4f / 127.0f);
}

extern "C" void kernel_launch(void* const* d_in, const int* in_sizes, int n_in,
                              void* d_out, int out_size, void* d_ws,
                              size_t ws_size, hipStream_t stream) {
  const float* cores = (const float*)d_in[0];
  float* out = (float*)d_out;
  float* ws = (float*)d_ws;

  float* accum = ws;          // 1 float
  float* sinv = ws + 64;      // 128 floats
  float* ssq = ws + 192;      // 128 floats
  float* big = ws + 1024;

  const int NBONDS = 127;
  const long CORE = 262144L;  // 256*4*256 floats per core

  // 4 ping-pong buffers of CH bonds each; size chunk from available workspace
  const size_t avail_f = ws_size / sizeof(float);
  int CH = 1;
  if (avail_f > 2048) {
    long c = (long)((avail_f - 1024) / (4 * PB));
    if (c < 1) c = 1;
    if (c > NBONDS) c = NBONDS;
    CH = (int)c;
  }
  float* B1 = big;
  float* B2 = B1 + (long)CH * PB;
  float* B3 = B2 + (long)CH * PB;
  float* B4 = B3 + (long)CH * PB;

  zero_k<<<1, 64, 0, stream>>>(accum);

  for (int b0 = 0; b0 < NBONDS; b0 += CH) {
    const int nb = (NBONDS - b0 < CH) ? (NBONDS - b0) : CH;
    const float* M0 = cores + (long)b0 * CORE;

    // G_b = M_b^T M_b  (K=1024) -> B1
    gemm_k<true><<<dim3(16, nb), 256, 0, stream>>>(M0, CORE, M0, CORE, B1, PB,
                                                   1024, 1.0f, 0.0f);
    pow_iter_k<<<nb, 256, 0, stream>>>(B1, sinv, ssq);
    init_yz_k<<<nb * 256, 256, 0, stream>>>(B1, B2, sinv);

    float* Y = B1;
    float* Z = B2;
    float* W = B3;
    float* S = B4;
    for (int it = 0; it < 10; ++it) {
      // W = 1.5 I - 0.5 * Z*Y
      gemm_k<false><<<dim3(16, nb), 256, 0, stream>>>(Z, PB, Y, PB, W, PB, 256,
                                                      -0.5f, 1.5f);
      float* Yn = S;  // Yn = Y*W
      gemm_k<false><<<dim3(16, nb), 256, 0, stream>>>(Y, PB, W, PB, Yn, PB, 256,
                                                      1.0f, 0.0f);
      float* Zn = Y;  // Zn = W*Z (old Y slot is free after Yn computed)
      gemm_k<false><<<dim3(16, nb), 256, 0, stream>>>(W, PB, Z, PB, Zn, PB, 256,
                                                      1.0f, 0.0f);
      S = Z;
      Y = Yn;
      Z = Zn;
    }
    trace_k<<<nb, 256, 0, stream>>>(Y, ssq, accum);
  }

  fin_k<<<1, 64, 0, stream>>>(accum, out);
}

// Round 2
// 663.821 us; speedup vs baseline: 3.5834x; 3.5834x over previous
//
#include <hip/hip_runtime.h>

typedef unsigned short ushort_t;
typedef __attribute__((ext_vector_type(8))) short short8v;
typedef __attribute__((ext_vector_type(8))) unsigned short ushort8v;
typedef __attribute__((ext_vector_type(4))) float f32x4;

__device__ __forceinline__ ushort_t f2bf(float f) {
  unsigned u = __float_as_uint(f);
  return (ushort_t)((u + 0x7FFFu + ((u >> 16) & 1u)) >> 16);  // RNE
}
__device__ __forceinline__ float bf2f(ushort_t h) {
  return __uint_as_float(((unsigned)h) << 16);
}

__device__ __forceinline__ void gload16(const void* g, void* l) {
  __builtin_amdgcn_global_load_lds(
      (const __attribute__((address_space(1))) void*)g,
      (__attribute__((address_space(3))) void*)l, 16, 0, 0);
}

// ---------------------------------------------------------------------------
// Convert fp32 M [1024][256] -> bf16 Mt [256][1024] (transpose), per bond.
// grid (64, nb): blockIdx.x: tk = x>>2 (k-tile 0..15), ti = x&3 (i-tile 0..3)
__global__ __launch_bounds__(256) void conv_t_k(const float* __restrict__ cores,
                                                ushort_t* __restrict__ Mt,
                                                int b0) {
  __shared__ float tile[64][65];
  const int t = threadIdx.x;
  const int tk = blockIdx.x >> 2;
  const int ti = blockIdx.x & 3;
  const float* src = cores + (long)(b0 + blockIdx.y) * 262144 +
                     (long)tk * 64 * 256 + ti * 64;
  ushort_t* dst = Mt + (long)blockIdx.y * 262144 + (long)ti * 64 * 1024 + tk * 64;

  const int r = t >> 4;
  const int c4 = (t & 15) * 4;
#pragma unroll
  for (int it = 0; it < 4; ++it) {
    const float4 v = *(const float4*)&src[(long)(r + it * 16) * 256 + c4];
    tile[r + it * 16][c4 + 0] = v.x;
    tile[r + it * 16][c4 + 1] = v.y;
    tile[r + it * 16][c4 + 2] = v.z;
    tile[r + it * 16][c4 + 3] = v.w;
  }
  __syncthreads();
#pragma unroll
  for (int it = 0; it < 2; ++it) {
    const int i = (t >> 3) + it * 32;
    const int k8 = (t & 7) * 8;
    ushort8v o;
#pragma unroll
    for (int j = 0; j < 8; ++j) o[j] = f2bf(tile[k8 + j][i]);
    *(ushort8v*)&dst[(long)i * 1024 + k8] = o;
  }
}

// ---------------------------------------------------------------------------
// NT GEMM: C = A * B^T (A [M=256][K] bf16 ld=lda, B [N=256][K] bf16 ld=ldb),
// C [256][256] bf16. EPI==1: C = 1.5I - 0.5*(A*B^T).
// grid (4, nb): 2x2 tiles of 128x128; 256 threads = 4 waves of 64x64.
template <int EPI>
__global__ __launch_bounds__(256) void gemm_nt_k(
    const ushort_t* __restrict__ Ab, long strideA, int lda,
    const ushort_t* __restrict__ Bb, long strideB, int ldb,
    ushort_t* __restrict__ Cb, long strideC, int K) {
  __shared__ ushort_t lds[2][128][64];  // [op][row][k], k XOR-swizzled, 32 KB

  const int t = threadIdx.x;
  const int ti = blockIdx.x >> 1, tj = blockIdx.x & 1;
  const ushort_t* A = Ab + (long)blockIdx.y * strideA + (long)ti * 128 * lda;
  const ushort_t* B = Bb + (long)blockIdx.y * strideB + (long)tj * 128 * ldb;
  ushort_t* C = Cb + (long)blockIdx.y * strideC;

  const int lane = t & 63;
  const int lr = lane & 15;
  const int lk = lane >> 4;
  const int wid = t >> 6;
  const int wr = wid >> 1, wc = wid & 1;

  f32x4 acc[4][4];
#pragma unroll
  for (int i = 0; i < 4; ++i)
#pragma unroll
    for (int j = 0; j < 4; ++j) acc[i][j] = (f32x4){0.f, 0.f, 0.f, 0.f};

  const int NK = K >> 6;
  for (int ks = 0; ks < NK; ++ks) {
    const int k0 = ks << 6;
    // stage: LDS linear dest (hw requirement), inverse-swizzled global source
#pragma unroll
    for (int is = 0; is < 4; ++is) {
      const int o = is * 2048 + t * 8;      // ushort offset in [128][64]
      const int row = o >> 6;
      const int kseg = (o >> 3) & 7;
      const int gseg = kseg ^ (row & 7);
      gload16(&A[(long)row * lda + k0 + gseg * 8], (char*)&lds[0][0][0] + o * 2);
      gload16(&B[(long)row * ldb + k0 + gseg * 8], (char*)&lds[1][0][0] + o * 2);
    }
    __syncthreads();  // drains vmcnt -> staged data visible
#pragma unroll
    for (int s = 0; s < 2; ++s) {
      short8v a[4], b[4];
#pragma unroll
      for (int f = 0; f < 4; ++f) {
        const int ra = wr * 64 + f * 16 + lr;
        const int ka = ((s * 4 + lk) ^ (ra & 7)) * 8;
        a[f] = *(const short8v*)&lds[0][ra][ka];
        const int rb = wc * 64 + f * 16 + lr;
        const int kb = ((s * 4 + lk) ^ (rb & 7)) * 8;
        b[f] = *(const short8v*)&lds[1][rb][kb];
      }
#pragma unroll
      for (int i = 0; i < 4; ++i)
#pragma unroll
        for (int j = 0; j < 4; ++j)
          acc[i][j] = __builtin_amdgcn_mfma_f32_16x16x32_bf16(a[i], b[j],
                                                              acc[i][j], 0, 0, 0);
    }
    __syncthreads();  // all reads done before next stage overwrites
  }

  // epilogue: C/D layout col=lane&15, row=(lane>>4)*4+reg  [guide §3, m89/m91]
#pragma unroll
  for (int i = 0; i < 4; ++i) {
    const int rowb = ti * 128 + wr * 64 + i * 16 + lk * 4;
#pragma unroll
    for (int j = 0; j < 4; ++j) {
      const int col = tj * 128 + wc * 64 + j * 16 + lr;
#pragma unroll
      for (int r = 0; r < 4; ++r) {
        float x = acc[i][j][r];
        const int row = rowb + r;
        if (EPI == 1) x = ((row == col) ? 1.5f : 0.0f) - 0.5f * x;
        C[(long)row * 256 + col] = f2bf(x);
      }
    }
  }
}

// ---------------------------------------------------------------------------
// Power iteration (6 steps) on bf16 G -> sinv = 1/s, ssq = sqrt(s), s=1.1*lam.
__global__ __launch_bounds__(256) void pow_iter_k(const ushort_t* __restrict__ Gb,
                                                  float* __restrict__ sinv,
                                                  float* __restrict__ ssq) {
  const ushort_t* G = Gb + (long)blockIdx.x * 65536;
  __shared__ float v[256];
  __shared__ float red[256];
  const int i = threadIdx.x;
  v[i] = 1.0f;
  __syncthreads();
  float lam = 1.0f;
  for (int it = 0; it < 6; ++it) {
    float wv = 0.f;
    for (int j = 0; j < 256; ++j) wv += bf2f(G[(long)j * 256 + i]) * v[j];
    red[i] = v[i] * wv;
    __syncthreads();
    for (int s = 128; s > 0; s >>= 1) {
      if (i < s) red[i] += red[i + s];
      __syncthreads();
    }
    const float vw = red[0];
    __syncthreads();
    red[i] = wv * wv;
    __syncthreads();
    for (int s = 128; s > 0; s >>= 1) {
      if (i < s) red[i] += red[i + s];
      __syncthreads();
    }
    const float ww = red[0];
    __syncthreads();
    lam = vw;  // Rayleigh quotient (v unit); never exceeds lambda_max
    v[i] = wv * rsqrtf(fmaxf(ww, 1e-30f));
    __syncthreads();
  }
  if (i == 0) {
    const float s = 1.10f * lam;
    sinv[blockIdx.x] = 1.0f / s;
    ssq[blockIdx.x] = sqrtf(s);
  }
}

// Y = bf16(G * sinv[b]) in place; Z = I (bf16). 8 elems/thread.
__global__ __launch_bounds__(256) void init_yz_k(ushort_t* __restrict__ Y,
                                                 ushort_t* __restrict__ Z,
                                                 const float* __restrict__ sinv) {
  const long e = ((long)blockIdx.x * 256 + threadIdx.x) * 8;
  const int b = (int)(e >> 16);
  const float s = sinv[b];
  const int w = (int)(e & 65535);
  const int i = w >> 8, j0 = w & 255;
  ushort8v y = *(const ushort8v*)&Y[e];
  ushort8v z;
#pragma unroll
  for (int j = 0; j < 8; ++j) {
    y[j] = f2bf(bf2f(y[j]) * s);
    z[j] = (i == j0 + j) ? (ushort_t)0x3F80 : (ushort_t)0;
  }
  *(ushort8v*)&Y[e] = y;
  *(ushort8v*)&Z[e] = z;
}

// tr(Y*W) = sum(Y o W) (both symmetric bf16); accum += ssq[b] * tr.
__global__ __launch_bounds__(256) void trace_dot_k(const ushort_t* __restrict__ Yb,
                                                   const ushort_t* __restrict__ Wb,
                                                   const float* __restrict__ ssq,
                                                   float* __restrict__ accum) {
  const int b = blockIdx.x;
  const long base = (long)b * 65536;
  const int t = threadIdx.x;
  float sum = 0.f;
  for (int it = 0; it < 32; ++it) {
    const long o = base + it * 2048 + t * 8;
    const ushort8v y = *(const ushort8v*)&Yb[o];
    const ushort8v w = *(const ushort8v*)&Wb[o];
#pragma unroll
    for (int j = 0; j < 8; ++j) sum += bf2f(y[j]) * bf2f(w[j]);
  }
  __shared__ float red[256];
  red[t] = sum;
  __syncthreads();
  for (int s = 128; s > 0; s >>= 1) {
    if (t < s) red[t] += red[t + s];
    __syncthreads();
  }
  if (t == 0) atomicAdd(accum, ssq[b] * red[0]);
}

__global__ void zero_k(float* a) {
  if (threadIdx.x == 0) a[0] = 0.f;
}
__global__ void fin_k(const float* __restrict__ accum, float* __restrict__ out) {
  if (threadIdx.x == 0) out[0] = accum[0] * (1e-4f / 127.0f);
}

// ---------------------------------------------------------------------------
extern "C" void kernel_launch(void* const* d_in, const int* in_sizes, int n_in,
                              void* d_out, int out_size, void* d_ws,
                              size_t ws_size, hipStream_t stream) {
  const float* cores = (const float*)d_in[0];
  float* out = (float*)d_out;
  char* w = (char*)d_ws;

  float* accum = (float*)w;   // 1
  float* sinv = accum + 64;   // 128
  float* ssq = sinv + 128;    // 128
  ushort_t* heap = (ushort_t*)(w + 4096);

  const int NB = 127;
  // per-bond ushorts: Mt 262144 + 4 * 65536 = 524288 (1 MiB)
  long ch = ((long)ws_size - 4096) / (524288L * 2);
  int CH = (ch < 1) ? 1 : ((ch > NB) ? NB : (int)ch);

  ushort_t* Mt = heap;
  ushort_t* P1 = Mt + (long)CH * 262144;
  ushort_t* P2 = P1 + (long)CH * 65536;
  ushort_t* P3 = P2 + (long)CH * 65536;
  ushort_t* P4 = P3 + (long)CH * 65536;

  zero_k<<<1, 64, 0, stream>>>(accum);

  for (int b0 = 0; b0 < NB; b0 += CH) {
    const int nb = (NB - b0 < CH) ? (NB - b0) : CH;

    conv_t_k<<<dim3(64, nb), 256, 0, stream>>>(cores, Mt, b0);

    // G = Mt * Mt^T  (K=1024) -> P1 (bf16)
    gemm_nt_k<0><<<dim3(4, nb), 256, 0, stream>>>(Mt, 262144, 1024, Mt, 262144,
                                                  1024, P1, 65536, 1024);
    pow_iter_k<<<nb, 256, 0, stream>>>(P1, sinv, ssq);
    init_yz_k<<<nb * 32, 256, 0, stream>>>(P1, P2, sinv);

    ushort_t *Y = P1, *Z = P2, *W = P3, *S = P4;
    for (int it = 0; it < 8; ++it) {
      // W = 1.5I - 0.5 * Z*Y   (all symmetric -> NT form)
      gemm_nt_k<1><<<dim3(4, nb), 256, 0, stream>>>(Z, 65536, 256, Y, 65536, 256,
                                                    W, 65536, 256);
      // Yn = Y*W -> S
      gemm_nt_k<0><<<dim3(4, nb), 256, 0, stream>>>(Y, 65536, 256, W, 65536, 256,
                                                    S, 65536, 256);
      // Zn = W*Z -> old Y slot
      gemm_nt_k<0><<<dim3(4, nb), 256, 0, stream>>>(W, 65536, 256, Z, 65536, 256,
                                                    Y, 65536, 256);
      ushort_t* nY = S;
      ushort_t* nZ = Y;
      ushort_t* nS = Z;
      Y = nY; Z = nZ; S = nS;
    }
    // final: W = 1.5I - 0.5*Z*Y, then tr(Y_next) = sum(Y o W)
    gemm_nt_k<1><<<dim3(4, nb), 256, 0, stream>>>(Z, 65536, 256, Y, 65536, 256,
                                                  W, 65536, 256);
    trace_dot_k<<<nb, 256, 0, stream>>>(Y, W, ssq, accum);
  }

  fin_k<<<1, 64, 0, stream>>>(accum, out);
}

// Round 3
// 416.808 us; speedup vs baseline: 5.7071x; 1.5926x over previous
//
#include <hip/hip_runtime.h>
#include <math.h>

typedef unsigned short ushort_t;
typedef __attribute__((ext_vector_type(8))) short short8v;
typedef __attribute__((ext_vector_type(8))) unsigned short ushort8v;
typedef __attribute__((ext_vector_type(4))) float f32x4;

__device__ __forceinline__ ushort_t f2bf(float f) {
  unsigned u = __float_as_uint(f);
  return (ushort_t)((u + 0x7FFFu + ((u >> 16) & 1u)) >> 16);  // RNE
}
__device__ __forceinline__ float bf2f(ushort_t h) {
  return __uint_as_float(((unsigned)h) << 16);
}

__device__ __forceinline__ void gload16(const void* g, void* l) {
  __builtin_amdgcn_global_load_lds(
      (const __attribute__((address_space(1))) void*)g,
      (__attribute__((address_space(3))) void*)l, 16, 0, 0);
}

// ---------------------------------------------------------------------------
// Convert fp32 M [1024][256] -> bf16 Mt [256][1024] (transpose), per bond.
__global__ __launch_bounds__(256) void conv_t_k(const float* __restrict__ cores,
                                                ushort_t* __restrict__ Mt,
                                                int b0) {
  __shared__ float tile[64][65];
  const int t = threadIdx.x;
  const int tk = blockIdx.x >> 2;
  const int ti = blockIdx.x & 3;
  const float* src = cores + (long)(b0 + blockIdx.y) * 262144 +
                     (long)tk * 64 * 256 + ti * 64;
  ushort_t* dst = Mt + (long)blockIdx.y * 262144 + (long)ti * 64 * 1024 + tk * 64;

  const int r = t >> 4;
  const int c4 = (t & 15) * 4;
#pragma unroll
  for (int it = 0; it < 4; ++it) {
    const float4 v = *(const float4*)&src[(long)(r + it * 16) * 256 + c4];
    tile[r + it * 16][c4 + 0] = v.x;
    tile[r + it * 16][c4 + 1] = v.y;
    tile[r + it * 16][c4 + 2] = v.z;
    tile[r + it * 16][c4 + 3] = v.w;
  }
  __syncthreads();
#pragma unroll
  for (int it = 0; it < 2; ++it) {
    const int i = (t >> 3) + it * 32;
    const int k8 = (t & 7) * 8;
    ushort8v o;
#pragma unroll
    for (int j = 0; j < 8; ++j) o[j] = f2bf(tile[k8 + j][i]);
    *(ushort8v*)&dst[(long)i * 1024 + k8] = o;
  }
}

// ---------------------------------------------------------------------------
// Batched 2-job NT GEMM: C = A * B^T, all 256x256 outputs, bf16 in/out.
// blockIdx.z selects job. grid (4, nb, nz); 256 threads = 4 waves of 64x64.
__global__ __launch_bounds__(256) void gemm_nt2_k(
    const ushort_t* __restrict__ A0, const ushort_t* __restrict__ B0,
    ushort_t* __restrict__ C0, const ushort_t* __restrict__ A1,
    const ushort_t* __restrict__ B1, ushort_t* __restrict__ C1,
    long strideA, long strideB, long strideC, int lda, int ldb, int K) {
  __shared__ ushort_t lds[2][128][64];  // [op][row][k], k XOR-swizzled, 32 KB

  const int t = threadIdx.x;
  const int ti = blockIdx.x >> 1, tj = blockIdx.x & 1;
  const ushort_t* Ab = blockIdx.z ? A1 : A0;
  const ushort_t* Bb = blockIdx.z ? B1 : B0;
  ushort_t* Cb = blockIdx.z ? C1 : C0;
  const ushort_t* A = Ab + (long)blockIdx.y * strideA + (long)ti * 128 * lda;
  const ushort_t* B = Bb + (long)blockIdx.y * strideB + (long)tj * 128 * ldb;
  ushort_t* C = Cb + (long)blockIdx.y * strideC;

  const int lane = t & 63;
  const int lr = lane & 15;
  const int lk = lane >> 4;
  const int wid = t >> 6;
  const int wr = wid >> 1, wc = wid & 1;

  f32x4 acc[4][4];
#pragma unroll
  for (int i = 0; i < 4; ++i)
#pragma unroll
    for (int j = 0; j < 4; ++j) acc[i][j] = (f32x4){0.f, 0.f, 0.f, 0.f};

  const int NK = K >> 6;
  for (int ks = 0; ks < NK; ++ks) {
    const int k0 = ks << 6;
#pragma unroll
    for (int is = 0; is < 4; ++is) {
      const int o = is * 2048 + t * 8;  // ushort offset in [128][64]
      const int row = o >> 6;
      const int kseg = (o >> 3) & 7;
      const int gseg = kseg ^ (row & 7);
      gload16(&A[(long)row * lda + k0 + gseg * 8], (char*)&lds[0][0][0] + o * 2);
      gload16(&B[(long)row * ldb + k0 + gseg * 8], (char*)&lds[1][0][0] + o * 2);
    }
    __syncthreads();
#pragma unroll
    for (int s = 0; s < 2; ++s) {
      short8v a[4], b[4];
#pragma unroll
      for (int f = 0; f < 4; ++f) {
        const int ra = wr * 64 + f * 16 + lr;
        const int ka = ((s * 4 + lk) ^ (ra & 7)) * 8;
        a[f] = *(const short8v*)&lds[0][ra][ka];
        const int rb = wc * 64 + f * 16 + lr;
        const int kb = ((s * 4 + lk) ^ (rb & 7)) * 8;
        b[f] = *(const short8v*)&lds[1][rb][kb];
      }
#pragma unroll
      for (int i = 0; i < 4; ++i)
#pragma unroll
        for (int j = 0; j < 4; ++j)
          acc[i][j] = __builtin_amdgcn_mfma_f32_16x16x32_bf16(a[i], b[j],
                                                              acc[i][j], 0, 0, 0);
    }
    __syncthreads();
  }

#pragma unroll
  for (int i = 0; i < 4; ++i) {
    const int rowb = ti * 128 + wr * 64 + i * 16 + lk * 4;
#pragma unroll
    for (int j = 0; j < 4; ++j) {
      const int col = tj * 128 + wc * 64 + j * 16 + lr;
#pragma unroll
      for (int r = 0; r < 4; ++r)
        C[(long)(rowb + r) * 256 + col] = f2bf(acc[i][j][r]);
    }
  }
}

// ---------------------------------------------------------------------------
// Power iteration (10 steps) on bf16 G -> sinv = 1/s, ssq = sqrt(s), s=1.06*R.
__global__ __launch_bounds__(256) void pow_iter_k(const ushort_t* __restrict__ Gb,
                                                  float* __restrict__ sinv,
                                                  float* __restrict__ ssq) {
  const ushort_t* G = Gb + (long)blockIdx.x * 65536;
  __shared__ float v[256];
  __shared__ float red[256];
  const int i = threadIdx.x;
  v[i] = 1.0f;
  __syncthreads();
  float lam = 1.0f;
  for (int it = 0; it < 10; ++it) {
    float wv = 0.f;
#pragma unroll 8
    for (int j = 0; j < 256; ++j) wv += bf2f(G[(long)j * 256 + i]) * v[j];
    red[i] = v[i] * wv;
    __syncthreads();
    for (int s = 128; s > 0; s >>= 1) {
      if (i < s) red[i] += red[i + s];
      __syncthreads();
    }
    const float vw = red[0];
    __syncthreads();
    red[i] = wv * wv;
    __syncthreads();
    for (int s = 128; s > 0; s >>= 1) {
      if (i < s) red[i] += red[i + s];
      __syncthreads();
    }
    const float ww = red[0];
    __syncthreads();
    lam = vw;  // Rayleigh quotient (v unit) <= lambda_max
    v[i] = wv * rsqrtf(fmaxf(ww, 1e-30f));
    __syncthreads();
  }
  if (i == 0) {
    const float s = 1.06f * lam;
    sinv[blockIdx.x] = 1.0f / s;
    ssq[blockIdx.x] = sqrtf(s);
  }
}

// t = c0 * G * sinv[b] - c1 * I   (in place on G, bf16), 8 elems/thread
__global__ __launch_bounds__(256) void scale_k(ushort_t* __restrict__ T,
                                               const float* __restrict__ sinv,
                                               float c0, float c1) {
  const long e = ((long)blockIdx.x * 256 + threadIdx.x) * 8;
  const int b = (int)(e >> 16);
  const float sc = sinv[b] * c0;
  const int w = (int)(e & 65535);
  const int i = w >> 8, j0 = w & 255;
  ushort8v v = *(const ushort8v*)&T[e];
#pragma unroll
  for (int j = 0; j < 8; ++j) {
    float f = bf2f(v[j]) * sc - ((i == j0 + j) ? c1 : 0.f);
    v[j] = f2bf(f);
  }
  *(ushort8v*)&T[e] = v;
}

// ---------------------------------------------------------------------------
struct Coefs {
  float a[21];
};

// Per bond: S_k = tr(t^k), k=0..20, from Frobenius pairs of
// {t, t2, t3, t4, t8, t12, t16}; accum += ssq[b] * sum_k a[k]*S_k.
__global__ __launch_bounds__(256) void dot_k(
    const ushort_t* __restrict__ T1, const ushort_t* __restrict__ T2,
    const ushort_t* __restrict__ T3, const ushort_t* __restrict__ T4,
    const ushort_t* __restrict__ T8, const ushort_t* __restrict__ T12,
    const ushort_t* __restrict__ T16, const float* __restrict__ ssq,
    float* __restrict__ accum, Coefs cf) {
  const int b = blockIdx.x;
  const long base = (long)b * 65536;
  const int t = threadIdx.x;
  const int lane = t & 63;
  const int wid = t >> 6;

  float s[21];
#pragma unroll
  for (int k = 0; k < 21; ++k) s[k] = 0.f;

  for (int it = 0; it < 32; ++it) {
    const int off = it * 2048 + t * 8;
    const long o = base + off;
    const int row = off >> 8, col0 = off & 255;
    const ushort8v v1 = *(const ushort8v*)&T1[o];
    const ushort8v v2 = *(const ushort8v*)&T2[o];
    const ushort8v v3 = *(const ushort8v*)&T3[o];
    const ushort8v v4 = *(const ushort8v*)&T4[o];
    const ushort8v v8 = *(const ushort8v*)&T8[o];
    const ushort8v v12 = *(const ushort8v*)&T12[o];
    const ushort8v v16 = *(const ushort8v*)&T16[o];
#pragma unroll
    for (int j = 0; j < 8; ++j) {
      const float x1 = bf2f(v1[j]), x2 = bf2f(v2[j]), x3 = bf2f(v3[j]);
      const float x4 = bf2f(v4[j]), x8 = bf2f(v8[j]), x12 = bf2f(v12[j]);
      const float x16 = bf2f(v16[j]);
      if (col0 + j == row) s[1] += x1;
      s[2] += x1 * x1;
      s[3] += x1 * x2;
      s[4] += x2 * x2;
      s[5] += x2 * x3;
      s[6] += x3 * x3;
      s[7] += x3 * x4;
      s[8] += x4 * x4;
      s[9] += x8 * x1;
      s[10] += x8 * x2;
      s[11] += x8 * x3;
      s[12] += x8 * x4;
      s[13] += x12 * x1;
      s[14] += x12 * x2;
      s[15] += x12 * x3;
      s[16] += x12 * x4;
      s[17] += x16 * x1;
      s[18] += x16 * x2;
      s[19] += x16 * x3;
      s[20] += x16 * x4;
    }
  }

  __shared__ float wred[4][21];
#pragma unroll
  for (int k = 1; k < 21; ++k) {
    float v = s[k];
    for (int m = 1; m < 64; m <<= 1) v += __shfl_xor(v, m, 64);
    if (lane == 0) wred[wid][k] = v;
  }
  __syncthreads();
  if (wid == 0) {
    float val = 0.f;
    if (lane >= 1 && lane < 21) {
      const float tot =
          wred[0][lane] + wred[1][lane] + wred[2][lane] + wred[3][lane];
      val = cf.a[lane] * tot;
    }
    for (int m = 1; m < 64; m <<= 1) val += __shfl_xor(val, m, 64);
    if (lane == 0) atomicAdd(accum, ssq[b] * (val + cf.a[0] * 256.0f));
  }
}

__global__ void zero_k(float* a) {
  if (threadIdx.x == 0) a[0] = 0.f;
}
__global__ void fin_k(const float* __restrict__ accum, float* __restrict__ out) {
  if (threadIdx.x == 0) out[0] = accum[0] * (1e-4f / 127.0f);
}

// ---------------------------------------------------------------------------
extern "C" void kernel_launch(void* const* d_in, const int* in_sizes, int n_in,
                              void* d_out, int out_size, void* d_ws,
                              size_t ws_size, hipStream_t stream) {
  const float* cores = (const float*)d_in[0];
  float* out = (float*)d_out;
  char* w = (char*)d_ws;

  // Host-side: degree-20 Chebyshev fit of sqrt(x) on [lo,hi], converted to
  // monomial basis in t (t = (2x-(hi+lo))/(hi-lo)). Deterministic每 call.
  const double lo = 0.06, hi = 1.05;
  const int DEG = 20, MQ = 64;
  double c[21];
  for (int k = 0; k <= DEG; ++k) {
    double sum = 0.0;
    for (int j = 0; j < MQ; ++j) {
      const double th = M_PI * (j + 0.5) / MQ;
      const double tt = cos(th);
      const double x = 0.5 * ((hi - lo) * tt + (hi + lo));
      sum += sqrt(x) * cos(k * th);
    }
    c[k] = 2.0 * sum / MQ;
  }
  c[0] *= 0.5;
  double Tp[21] = {0}, Tc[21] = {0}, am[21] = {0};
  Tp[0] = 1.0;  // T_0
  am[0] += c[0] * Tp[0];
  Tc[1] = 1.0;  // T_1
  am[1] += c[1] * Tc[1];
  for (int k = 2; k <= DEG; ++k) {
    double Tn[21] = {0};
    for (int m = 0; m <= DEG; ++m) {
      const double sh = (m > 0) ? 2.0 * Tc[m - 1] : 0.0;
      Tn[m] = sh - Tp[m];
    }
    for (int m = 0; m <= DEG; ++m) am[m] += c[k] * Tn[m];
    for (int m = 0; m <= DEG; ++m) {
      Tp[m] = Tc[m];
      Tc[m] = Tn[m];
    }
  }
  Coefs cf;
  for (int m = 0; m <= DEG; ++m) cf.a[m] = (float)am[m];
  const float c0 = (float)(2.0 / (hi - lo));
  const float c1 = (float)((hi + lo) / (hi - lo));

  float* accum = (float*)w;  // 1
  float* sinv = accum + 64;  // 128
  float* ssq = sinv + 128;   // 128
  ushort_t* heap = (ushort_t*)(w + 4096);

  const int NB = 127;
  // per-bond ushorts: Mt 262144 + 7 * 65536 = 720896 (1.44 MB)
  long ch = ((long)ws_size - 4096) / (720896L * 2);
  int CH = (ch < 1) ? 1 : ((ch > NB) ? NB : (int)ch);

  ushort_t* Mt = heap;
  ushort_t* T1 = Mt + (long)CH * 262144;
  ushort_t* T2 = T1 + (long)CH * 65536;
  ushort_t* T3 = T2 + (long)CH * 65536;
  ushort_t* T4 = T3 + (long)CH * 65536;
  ushort_t* T8 = T4 + (long)CH * 65536;
  ushort_t* T12 = T8 + (long)CH * 65536;
  ushort_t* T16 = T12 + (long)CH * 65536;

  zero_k<<<1, 64, 0, stream>>>(accum);

  for (int b0 = 0; b0 < NB; b0 += CH) {
    const int nb = (NB - b0 < CH) ? (NB - b0) : CH;

    conv_t_k<<<dim3(64, nb), 256, 0, stream>>>(cores, Mt, b0);

    // G = Mt * Mt^T  (K=1024) -> T1
    gemm_nt2_k<<<dim3(4, nb, 1), 256, 0, stream>>>(
        Mt, Mt, T1, nullptr, nullptr, nullptr, 262144, 262144, 65536, 1024,
        1024, 1024);
    pow_iter_k<<<nb, 256, 0, stream>>>(T1, sinv, ssq);
    scale_k<<<nb * 32, 256, 0, stream>>>(T1, sinv, c0, c1);

    // t^2
    gemm_nt2_k<<<dim3(4, nb, 1), 256, 0, stream>>>(
        T1, T1, T2, nullptr, nullptr, nullptr, 65536, 65536, 65536, 256, 256,
        256);
    // t^3 = t2*t, t^4 = t2*t2
    gemm_nt2_k<<<dim3(4, nb, 2), 256, 0, stream>>>(
        T2, T1, T3, T2, T2, T4, 65536, 65536, 65536, 256, 256, 256);
    // t^8 = t4*t4
    gemm_nt2_k<<<dim3(4, nb, 1), 256, 0, stream>>>(
        T4, T4, T8, nullptr, nullptr, nullptr, 65536, 65536, 65536, 256, 256,
        256);
    // t^12 = t8*t4, t^16 = t8*t8
    gemm_nt2_k<<<dim3(4, nb, 2), 256, 0, stream>>>(
        T8, T4, T12, T8, T8, T16, 65536, 65536, 65536, 256, 256, 256);

    dot_k<<<nb, 256, 0, stream>>>(T1, T2, T3, T4, T8, T12, T16, ssq, accum, cf);
  }

  fin_k<<<1, 64, 0, stream>>>(accum, out);
}

// Round 4
// 374.815 us; speedup vs baseline: 6.3465x; 1.1120x over previous
//
#include <hip/hip_runtime.h>
#include <math.h>

typedef unsigned short ushort_t;
typedef __attribute__((ext_vector_type(8))) short short8v;
typedef __attribute__((ext_vector_type(8))) unsigned short ushort8v;
typedef __attribute__((ext_vector_type(4))) float f32x4;

__device__ __forceinline__ ushort_t f2bf(float f) {
  unsigned u = __float_as_uint(f);
  return (ushort_t)((u + 0x7FFFu + ((u >> 16) & 1u)) >> 16);  // RNE
}
__device__ __forceinline__ float bf2f(ushort_t h) {
  return __uint_as_float(((unsigned)h) << 16);
}
__device__ __forceinline__ float bflo(unsigned u) {
  return __uint_as_float(u << 16);
}
__device__ __forceinline__ float bfhi(unsigned u) {
  return __uint_as_float(u & 0xFFFF0000u);
}

__device__ __forceinline__ void gload16(const void* g, void* l) {
  __builtin_amdgcn_global_load_lds(
      (const __attribute__((address_space(1))) void*)g,
      (__attribute__((address_space(3))) void*)l, 16, 0, 0);
}

// ---------------------------------------------------------------------------
// Convert fp32 M [1024][256] -> bf16 Mt [256][1024] (transpose), per bond.
// Also zeroes the accumulator (block 0 only; stream order makes this safe).
__global__ __launch_bounds__(256) void conv_t_k(const float* __restrict__ cores,
                                                ushort_t* __restrict__ Mt,
                                                int b0, float* __restrict__ accum) {
  if (blockIdx.x == 0 && blockIdx.y == 0 && threadIdx.x == 0) accum[0] = 0.f;
  __shared__ float tile[64][65];
  const int t = threadIdx.x;
  const int tk = blockIdx.x >> 2;
  const int ti = blockIdx.x & 3;
  const float* src = cores + (long)(b0 + blockIdx.y) * 262144 +
                     (long)tk * 64 * 256 + ti * 64;
  ushort_t* dst = Mt + (long)blockIdx.y * 262144 + (long)ti * 64 * 1024 + tk * 64;

  const int r = t >> 4;
  const int c4 = (t & 15) * 4;
#pragma unroll
  for (int it = 0; it < 4; ++it) {
    const float4 v = *(const float4*)&src[(long)(r + it * 16) * 256 + c4];
    tile[r + it * 16][c4 + 0] = v.x;
    tile[r + it * 16][c4 + 1] = v.y;
    tile[r + it * 16][c4 + 2] = v.z;
    tile[r + it * 16][c4 + 3] = v.w;
  }
  __syncthreads();
#pragma unroll
  for (int it = 0; it < 2; ++it) {
    const int i = (t >> 3) + it * 32;
    const int k8 = (t & 7) * 8;
    ushort8v o;
#pragma unroll
    for (int j = 0; j < 8; ++j) o[j] = f2bf(tile[k8 + j][i]);
    *(ushort8v*)&dst[(long)i * 1024 + k8] = o;
  }
}

// ---------------------------------------------------------------------------
// Batched 2-job NT GEMM: C = A * B^T, 256x256 bf16 outputs. (proven r2 kernel)
__global__ __launch_bounds__(256) void gemm_nt2_k(
    const ushort_t* __restrict__ A0, const ushort_t* __restrict__ B0,
    ushort_t* __restrict__ C0, const ushort_t* __restrict__ A1,
    const ushort_t* __restrict__ B1, ushort_t* __restrict__ C1,
    long strideA, long strideB, long strideC, int lda, int ldb, int K) {
  __shared__ ushort_t lds[2][128][64];

  const int t = threadIdx.x;
  const int ti = blockIdx.x >> 1, tj = blockIdx.x & 1;
  const ushort_t* Ab = blockIdx.z ? A1 : A0;
  const ushort_t* Bb = blockIdx.z ? B1 : B0;
  ushort_t* Cb = blockIdx.z ? C1 : C0;
  const ushort_t* A = Ab + (long)blockIdx.y * strideA + (long)ti * 128 * lda;
  const ushort_t* B = Bb + (long)blockIdx.y * strideB + (long)tj * 128 * ldb;
  ushort_t* C = Cb + (long)blockIdx.y * strideC;

  const int lane = t & 63;
  const int lr = lane & 15;
  const int lk = lane >> 4;
  const int wid = t >> 6;
  const int wr = wid >> 1, wc = wid & 1;

  f32x4 acc[4][4];
#pragma unroll
  for (int i = 0; i < 4; ++i)
#pragma unroll
    for (int j = 0; j < 4; ++j) acc[i][j] = (f32x4){0.f, 0.f, 0.f, 0.f};

  const int NK = K >> 6;
  for (int ks = 0; ks < NK; ++ks) {
    const int k0 = ks << 6;
#pragma unroll
    for (int is = 0; is < 4; ++is) {
      const int o = is * 2048 + t * 8;
      const int row = o >> 6;
      const int kseg = (o >> 3) & 7;
      const int gseg = kseg ^ (row & 7);
      gload16(&A[(long)row * lda + k0 + gseg * 8], (char*)&lds[0][0][0] + o * 2);
      gload16(&B[(long)row * ldb + k0 + gseg * 8], (char*)&lds[1][0][0] + o * 2);
    }
    __syncthreads();
#pragma unroll
    for (int s = 0; s < 2; ++s) {
      short8v a[4], b[4];
#pragma unroll
      for (int f = 0; f < 4; ++f) {
        const int ra = wr * 64 + f * 16 + lr;
        const int ka = ((s * 4 + lk) ^ (ra & 7)) * 8;
        a[f] = *(const short8v*)&lds[0][ra][ka];
        const int rb = wc * 64 + f * 16 + lr;
        const int kb = ((s * 4 + lk) ^ (rb & 7)) * 8;
        b[f] = *(const short8v*)&lds[1][rb][kb];
      }
#pragma unroll
      for (int i = 0; i < 4; ++i)
#pragma unroll
        for (int j = 0; j < 4; ++j)
          acc[i][j] = __builtin_amdgcn_mfma_f32_16x16x32_bf16(a[i], b[j],
                                                              acc[i][j], 0, 0, 0);
    }
    __syncthreads();
  }

#pragma unroll
  for (int i = 0; i < 4; ++i) {
    const int rowb = ti * 128 + wr * 64 + i * 16 + lk * 4;
#pragma unroll
    for (int j = 0; j < 4; ++j) {
      const int col = tj * 128 + wc * 64 + j * 16 + lr;
#pragma unroll
      for (int r = 0; r < 4; ++r)
        C[(long)(rowb + r) * 256 + col] = f2bf(acc[i][j][r]);
    }
  }
}

// ---------------------------------------------------------------------------
// Fused: from G (bf16) and sinv, compute T1 = alpha*G - c1*I and
// T2 = alpha^2*G^2 - 2*alpha*c1*G + c1^2*I  (alpha = c0*sinv[b]).
__global__ __launch_bounds__(256) void gemm_t2_k(
    const ushort_t* __restrict__ Gb, const float* __restrict__ sinv,
    ushort_t* __restrict__ T1b, ushort_t* __restrict__ T2b, float c0, float c1) {
  __shared__ ushort_t lds[2][128][64];

  const int t = threadIdx.x;
  const int ti = blockIdx.x >> 1, tj = blockIdx.x & 1;
  const long base = (long)blockIdx.y * 65536;
  const ushort_t* A = Gb + base + (long)ti * 128 * 256;
  const ushort_t* B = Gb + base + (long)tj * 128 * 256;

  const int lane = t & 63;
  const int lr = lane & 15;
  const int lk = lane >> 4;
  const int wid = t >> 6;
  const int wr = wid >> 1, wc = wid & 1;

  f32x4 acc[4][4];
#pragma unroll
  for (int i = 0; i < 4; ++i)
#pragma unroll
    for (int j = 0; j < 4; ++j) acc[i][j] = (f32x4){0.f, 0.f, 0.f, 0.f};

  for (int ks = 0; ks < 4; ++ks) {
    const int k0 = ks << 6;
#pragma unroll
    for (int is = 0; is < 4; ++is) {
      const int o = is * 2048 + t * 8;
      const int row = o >> 6;
      const int kseg = (o >> 3) & 7;
      const int gseg = kseg ^ (row & 7);
      gload16(&A[(long)row * 256 + k0 + gseg * 8], (char*)&lds[0][0][0] + o * 2);
      gload16(&B[(long)row * 256 + k0 + gseg * 8], (char*)&lds[1][0][0] + o * 2);
    }
    __syncthreads();
#pragma unroll
    for (int s = 0; s < 2; ++s) {
      short8v a[4], b[4];
#pragma unroll
      for (int f = 0; f < 4; ++f) {
        const int ra = wr * 64 + f * 16 + lr;
        const int ka = ((s * 4 + lk) ^ (ra & 7)) * 8;
        a[f] = *(const short8v*)&lds[0][ra][ka];
        const int rb = wc * 64 + f * 16 + lr;
        const int kb = ((s * 4 + lk) ^ (rb & 7)) * 8;
        b[f] = *(const short8v*)&lds[1][rb][kb];
      }
#pragma unroll
      for (int i = 0; i < 4; ++i)
#pragma unroll
        for (int j = 0; j < 4; ++j)
          acc[i][j] = __builtin_amdgcn_mfma_f32_16x16x32_bf16(a[i], b[j],
                                                              acc[i][j], 0, 0, 0);
    }
    __syncthreads();
  }

  const float al = c0 * sinv[blockIdx.y];
  const float al2 = al * al;
  const float a2c = 2.0f * al * c1;
  const float c1sq = c1 * c1;
#pragma unroll
  for (int i = 0; i < 4; ++i) {
    const int rowb = ti * 128 + wr * 64 + i * 16 + lk * 4;
#pragma unroll
    for (int j = 0; j < 4; ++j) {
      const int col = tj * 128 + wc * 64 + j * 16 + lr;
#pragma unroll
      for (int r = 0; r < 4; ++r) {
        const int row = rowb + r;
        const long idx = base + (long)row * 256 + col;
        const float g = bf2f(Gb[idx]);
        const float dia = (row == col) ? 1.0f : 0.0f;
        T1b[idx] = f2bf(al * g - c1 * dia);
        T2b[idx] = f2bf(al2 * acc[i][j][r] - a2c * g + c1sq * dia);
      }
    }
  }
}

// ---------------------------------------------------------------------------
// Fast power iteration: G row per thread in registers (bf16 packed), v in LDS.
// 10 unnormalized matvecs (normalize at it 3,6), Rayleigh at end.
__global__ __launch_bounds__(256) void pow_fast_k(const ushort_t* __restrict__ Gb,
                                                  float* __restrict__ sinv,
                                                  float* __restrict__ ssq) {
  const int i = threadIdx.x;
  const ushort_t* Grow = Gb + (long)blockIdx.x * 65536 + (long)i * 256;
  uint4 g[32];
#pragma unroll
  for (int r = 0; r < 32; ++r) g[r] = *(const uint4*)&Grow[r * 8];

  __shared__ float v[256];
  __shared__ float rr[4];
  v[i] = 1.0f;
  __syncthreads();

  float w = 0.f;
  float num = 0.f, den = 1.f;
  for (int it = 0; it < 10; ++it) {
    float a0 = 0.f, a1 = 0.f, a2 = 0.f, a3 = 0.f;
#pragma unroll
    for (int r = 0; r < 32; ++r) {
      const float4 va = *(const float4*)&v[r * 8];
      const float4 vb = *(const float4*)&v[r * 8 + 4];
      const uint4 gg = g[r];
      a0 += bflo(gg.x) * va.x + bfhi(gg.x) * va.y;
      a1 += bflo(gg.y) * va.z + bfhi(gg.y) * va.w;
      a2 += bflo(gg.z) * vb.x + bfhi(gg.z) * vb.y;
      a3 += bflo(gg.w) * vb.z + bfhi(gg.w) * vb.w;
    }
    w = (a0 + a1) + (a2 + a3);

    if (it == 9) {
      // Rayleigh with pre-matvec vector still in LDS
      float pn = v[i] * w, pd = v[i] * v[i];
#pragma unroll
      for (int m = 1; m < 64; m <<= 1) {
        pn += __shfl_xor(pn, m, 64);
        pd += __shfl_xor(pd, m, 64);
      }
      __shared__ float rn[4], rd[4];
      if ((i & 63) == 0) {
        rn[i >> 6] = pn;
        rd[i >> 6] = pd;
      }
      __syncthreads();
      num = rn[0] + rn[1] + rn[2] + rn[3];
      den = rd[0] + rd[1] + rd[2] + rd[3];
      break;
    }

    if (it == 3 || it == 6) {
      float p = w * w;
#pragma unroll
      for (int m = 1; m < 64; m <<= 1) p += __shfl_xor(p, m, 64);
      if ((i & 63) == 0) rr[i >> 6] = p;
      __syncthreads();
      const float ww = rr[0] + rr[1] + rr[2] + rr[3];
      w *= rsqrtf(fmaxf(ww, 1e-30f));
    }
    __syncthreads();  // all reads of v done
    v[i] = w;
    __syncthreads();
  }

  if (i == 0) {
    const float lam = num / den;
    const float s = 1.06f * lam;
    sinv[blockIdx.x] = 1.0f / s;
    ssq[blockIdx.x] = sqrtf(s);
  }
}

// ---------------------------------------------------------------------------
struct Coefs {
  float a[21];
};

// Per bond: S_k = tr(t^k) from Frobenius pairs of {t,t2,t3,t4,t8,t12,t16}.
__global__ __launch_bounds__(256) void dot_k(
    const ushort_t* __restrict__ T1, const ushort_t* __restrict__ T2,
    const ushort_t* __restrict__ T3, const ushort_t* __restrict__ T4,
    const ushort_t* __restrict__ T8, const ushort_t* __restrict__ T12,
    const ushort_t* __restrict__ T16, const float* __restrict__ ssq,
    float* __restrict__ accum, Coefs cf) {
  const int b = blockIdx.x;
  const long base = (long)b * 65536;
  const int t = threadIdx.x;
  const int lane = t & 63;
  const int wid = t >> 6;

  float s[21];
#pragma unroll
  for (int k = 0; k < 21; ++k) s[k] = 0.f;

  for (int it = 0; it < 32; ++it) {
    const int off = it * 2048 + t * 8;
    const long o = base + off;
    const int row = off >> 8, col0 = off & 255;
    const ushort8v v1 = *(const ushort8v*)&T1[o];
    const ushort8v v2 = *(const ushort8v*)&T2[o];
    const ushort8v v3 = *(const ushort8v*)&T3[o];
    const ushort8v v4 = *(const ushort8v*)&T4[o];
    const ushort8v v8 = *(const ushort8v*)&T8[o];
    const ushort8v v12 = *(const ushort8v*)&T12[o];
    const ushort8v v16 = *(const ushort8v*)&T16[o];
#pragma unroll
    for (int j = 0; j < 8; ++j) {
      const float x1 = bf2f(v1[j]), x2 = bf2f(v2[j]), x3 = bf2f(v3[j]);
      const float x4 = bf2f(v4[j]), x8 = bf2f(v8[j]), x12 = bf2f(v12[j]);
      const float x16 = bf2f(v16[j]);
      if (col0 + j == row) s[1] += x1;
      s[2] += x1 * x1;
      s[3] += x1 * x2;
      s[4] += x2 * x2;
      s[5] += x2 * x3;
      s[6] += x3 * x3;
      s[7] += x3 * x4;
      s[8] += x4 * x4;
      s[9] += x8 * x1;
      s[10] += x8 * x2;
      s[11] += x8 * x3;
      s[12] += x8 * x4;
      s[13] += x12 * x1;
      s[14] += x12 * x2;
      s[15] += x12 * x3;
      s[16] += x12 * x4;
      s[17] += x16 * x1;
      s[18] += x16 * x2;
      s[19] += x16 * x3;
      s[20] += x16 * x4;
    }
  }

  __shared__ float wred[4][21];
#pragma unroll
  for (int k = 1; k < 21; ++k) {
    float v = s[k];
    for (int m = 1; m < 64; m <<= 1) v += __shfl_xor(v, m, 64);
    if (lane == 0) wred[wid][k] = v;
  }
  __syncthreads();
  if (wid == 0) {
    float val = 0.f;
    if (lane >= 1 && lane < 21) {
      const float tot =
          wred[0][lane] + wred[1][lane] + wred[2][lane] + wred[3][lane];
      val = cf.a[lane] * tot;
    }
    for (int m = 1; m < 64; m <<= 1) val += __shfl_xor(val, m, 64);
    if (lane == 0) atomicAdd(accum, ssq[b] * (val + cf.a[0] * 256.0f));
  }
}

__global__ void fin_k(const float* __restrict__ accum, float* __restrict__ out) {
  if (threadIdx.x == 0) out[0] = accum[0] * (1e-4f / 127.0f);
}

// ---------------------------------------------------------------------------
extern "C" void kernel_launch(void* const* d_in, const int* in_sizes, int n_in,
                              void* d_out, int out_size, void* d_ws,
                              size_t ws_size, hipStream_t stream) {
  const float* cores = (const float*)d_in[0];
  float* out = (float*)d_out;
  char* w = (char*)d_ws;

  // Host: degree-20 Chebyshev fit of sqrt(x) on [lo,hi] -> monomial in t.
  const double lo = 0.06, hi = 1.05;
  const int DEG = 20, MQ = 64;
  double c[21];
  for (int k = 0; k <= DEG; ++k) {
    double sum = 0.0;
    for (int j = 0; j < MQ; ++j) {
      const double th = M_PI * (j + 0.5) / MQ;
      const double tt = cos(th);
      const double x = 0.5 * ((hi - lo) * tt + (hi + lo));
      sum += sqrt(x) * cos(k * th);
    }
    c[k] = 2.0 * sum / MQ;
  }
  c[0] *= 0.5;
  double Tp[21] = {0}, Tc[21] = {0}, am[21] = {0};
  Tp[0] = 1.0;
  am[0] += c[0] * Tp[0];
  Tc[1] = 1.0;
  am[1] += c[1] * Tc[1];
  for (int k = 2; k <= DEG; ++k) {
    double Tn[21] = {0};
    for (int m = 0; m <= DEG; ++m) {
      const double sh = (m > 0) ? 2.0 * Tc[m - 1] : 0.0;
      Tn[m] = sh - Tp[m];
    }
    for (int m = 0; m <= DEG; ++m) am[m] += c[k] * Tn[m];
    for (int m = 0; m <= DEG; ++m) {
      Tp[m] = Tc[m];
      Tc[m] = Tn[m];
    }
  }
  Coefs cf;
  for (int m = 0; m <= DEG; ++m) cf.a[m] = (float)am[m];
  const float c0 = (float)(2.0 / (hi - lo));
  const float c1 = (float)((hi + lo) / (hi - lo));

  float* accum = (float*)w;
  float* sinv = accum + 64;
  float* ssq = sinv + 128;
  ushort_t* heap = (ushort_t*)(w + 4096);

  const int NB = 127;
  // per-bond ushorts: Mt 262144 + 8 * 65536 = 786432 (1.57 MB)
  long ch = ((long)ws_size - 4096) / (786432L * 2);
  int CH = (ch < 1) ? 1 : ((ch > NB) ? NB : (int)ch);

  ushort_t* Mt = heap;
  ushort_t* G = Mt + (long)CH * 262144;
  ushort_t* T1 = G + (long)CH * 65536;
  ushort_t* T2 = T1 + (long)CH * 65536;
  ushort_t* T3 = T2 + (long)CH * 65536;
  ushort_t* T4 = T3 + (long)CH * 65536;
  ushort_t* T8 = T4 + (long)CH * 65536;
  ushort_t* T12 = T8 + (long)CH * 65536;
  ushort_t* T16 = T12 + (long)CH * 65536;

  for (int b0 = 0; b0 < NB; b0 += CH) {
    const int nb = (NB - b0 < CH) ? (NB - b0) : CH;

    conv_t_k<<<dim3(64, nb), 256, 0, stream>>>(cores, Mt, b0, accum);

    // G = Mt * Mt^T  (K=1024)
    gemm_nt2_k<<<dim3(4, nb, 1), 256, 0, stream>>>(
        Mt, Mt, G, nullptr, nullptr, nullptr, 262144, 262144, 65536, 1024,
        1024, 1024);
    pow_fast_k<<<nb, 256, 0, stream>>>(G, sinv, ssq);

    // T1 = t, T2 = t^2 (fused scale + square)
    gemm_t2_k<<<dim3(4, nb, 1), 256, 0, stream>>>(G, sinv, T1, T2, c0, c1);
    // t^3 = t2*t, t^4 = t2*t2
    gemm_nt2_k<<<dim3(4, nb, 2), 256, 0, stream>>>(
        T2, T1, T3, T2, T2, T4, 65536, 65536, 65536, 256, 256, 256);
    // t^8 = t4*t4
    gemm_nt2_k<<<dim3(4, nb, 1), 256, 0, stream>>>(
        T4, T4, T8, nullptr, nullptr, nullptr, 65536, 65536, 65536, 256, 256,
        256);
    // t^12 = t8*t4, t^16 = t8*t8
    gemm_nt2_k<<<dim3(4, nb, 2), 256, 0, stream>>>(
        T8, T4, T12, T8, T8, T16, 65536, 65536, 65536, 256, 256, 256);

    dot_k<<<nb, 256, 0, stream>>>(T1, T2, T3, T4, T8, T12, T16, ssq, accum, cf);
  }

  fin_k<<<1, 64, 0, stream>>>(accum, out);
}